// Round 3
// baseline (964.582 us; speedup 1.0000x reference)
//
#include <hip/hip_runtime.h>
#include <math.h>

#define N_NODES 20000
#define N_EDGES 160000
#define NODE_DIM 64
#define EDGE_DIM 16
#define H 32
#define STEPS 3
#define UROW 544   // 17 planes of 32: U[v][d*32+i], d=16 is the b_e plane

// ---------------------------------------------------------------------------
// CSR build (once per call): hist -> 2-level exclusive scan -> atomic fill.
// deg/cursor share storage.
// ---------------------------------------------------------------------------
__global__ void hist_kernel(const int* __restrict__ ei, int* __restrict__ deg) {
    int e = blockIdx.x * 256 + threadIdx.x;
    if (e < N_EDGES) atomicAdd(&deg[ei[N_EDGES + e]], 1);
}

// 79 blocks x 256: per-block exclusive scan into part (=rowptr), block sums out
__global__ void scan_a_kernel(const int* __restrict__ deg,
                              int* __restrict__ part, int* __restrict__ bsum) {
    __shared__ int s[256];
    int v = blockIdx.x * 256 + threadIdx.x;
    int x = (v < N_NODES) ? deg[v] : 0;
    s[threadIdx.x] = x;
    __syncthreads();
    for (int off = 1; off < 256; off <<= 1) {
        int t = (threadIdx.x >= off) ? s[threadIdx.x - off] : 0;
        __syncthreads();
        s[threadIdx.x] += t;
        __syncthreads();
    }
    if (v < N_NODES) part[v] = s[threadIdx.x] - x;   // exclusive within block
    if (threadIdx.x == 255) bsum[blockIdx.x] = s[255];
}

// single block: scan the 79 block sums, add offsets, copy to cursor
__global__ void scan_b_kernel(int* __restrict__ rowptr,
                              const int* __restrict__ bsum,
                              int* __restrict__ cursor) {
    __shared__ int boff[80];
    if (threadIdx.x == 0) {
        int run = 0;
        for (int b = 0; b < 79; ++b) { boff[b] = run; run += bsum[b]; }
    }
    __syncthreads();
    for (int v = threadIdx.x; v < N_NODES; v += 256) {
        int r = rowptr[v] + boff[v >> 8];
        rowptr[v] = r;
        cursor[v] = r;
    }
    if (threadIdx.x == 0) rowptr[N_NODES] = N_EDGES;
}

__global__ void fill_kernel(const int* __restrict__ ei,
                            int* __restrict__ cursor, int* __restrict__ elist) {
    int e = blockIdx.x * 256 + threadIdx.x;
    if (e < N_EDGES) {
        int slot = atomicAdd(&cursor[ei[N_EDGES + e]], 1);
        elist[slot] = e;
    }
}

// ---------------------------------------------------------------------------
// node projection: h = node_feat @ W_np.T + b_np
// ---------------------------------------------------------------------------
__global__ void node_proj_kernel(const float* __restrict__ nf,
                                 const float* __restrict__ W,
                                 const float* __restrict__ b,
                                 float* __restrict__ h) {
    int tid = blockIdx.x * blockDim.x + threadIdx.x;
    if (tid >= N_NODES * H) return;
    int v = tid >> 5;
    int i = tid & 31;
    const float* __restrict__ row = nf + v * NODE_DIM;
    const float* __restrict__ w   = W + i * NODE_DIM;
    float acc = b[i];
#pragma unroll
    for (int d = 0; d < NODE_DIM; ++d) acc = fmaf(row[d], w[d], acc);
    h[tid] = acc;
}

// ---------------------------------------------------------------------------
// U precompute:  U[v, d*32+i] = sum_k W_e[(i*32+k)*16+d] * h[v,k]
//                U[v, 512+i]  = sum_k b_e[i*32+k]       * h[v,k]
// W_e slice in REGISTERS: wave w, lane L owns cols c = w*128 + L*2 + {0,1}
// (c<512; col c -> i=c&31, d=c>>5). h rows staged in 4 KB LDS, read by
// same-address broadcast ds_read_b128 (conflict-free). Wave 0 lanes<32
// additionally compute the bias plane (breg, 32 regs).
// 625 blocks x 32 nodes = 20000 exactly.
// ---------------------------------------------------------------------------
__global__ __launch_bounds__(256)
void u_precompute_kernel(const float* __restrict__ We,
                         const float* __restrict__ be,
                         const float* __restrict__ h,
                         float* __restrict__ U) {
    __shared__ float hs[32 * 32];   // 4 KB
    int tid  = threadIdx.x;
    int w    = tid >> 6;
    int lane = tid & 63;

    int c0 = w * 128 + lane * 2;
    int i0 = c0 & 31,       d0 = c0 >> 5;
    int i1 = (c0 + 1) & 31, d1 = (c0 + 1) >> 5;

    float2 wreg[32];
#pragma unroll
    for (int k = 0; k < H; ++k) {
        wreg[k].x = We[(i0 * H + k) * EDGE_DIM + d0];
        wreg[k].y = We[(i1 * H + k) * EDGE_DIM + d1];
    }
    bool doB = (w == 0) && (lane < 32);
    float breg[32];
    if (doB) {
#pragma unroll
        for (int k = 0; k < H; ++k) breg[k] = be[lane * H + k];
    }

    int vbase = blockIdx.x * 32;
    for (int t = tid; t < 32 * 32; t += 256) hs[t] = h[vbase * 32 + t];
    __syncthreads();

    for (int n = 0; n < 32; ++n) {
        const float4* __restrict__ hp = (const float4*)(hs + n * 32);
        float a0 = 0.f, a1 = 0.f;
#pragma unroll
        for (int kk = 0; kk < 8; ++kk) {
            float4 hq = hp[kk];
            a0 = fmaf(wreg[4 * kk + 0].x, hq.x, a0);
            a1 = fmaf(wreg[4 * kk + 0].y, hq.x, a1);
            a0 = fmaf(wreg[4 * kk + 1].x, hq.y, a0);
            a1 = fmaf(wreg[4 * kk + 1].y, hq.y, a1);
            a0 = fmaf(wreg[4 * kk + 2].x, hq.z, a0);
            a1 = fmaf(wreg[4 * kk + 2].y, hq.z, a1);
            a0 = fmaf(wreg[4 * kk + 3].x, hq.w, a0);
            a1 = fmaf(wreg[4 * kk + 3].y, hq.w, a1);
        }
        float* __restrict__ Up = U + (size_t)(vbase + n) * UROW;
        ((float2*)(Up + w * 128))[lane] = make_float2(a0, a1);

        if (doB) {
            float bacc = 0.f;
#pragma unroll
            for (int kk = 0; kk < 8; ++kk) {
                float4 hq = hp[kk];
                bacc = fmaf(breg[4 * kk + 0], hq.x, bacc);
                bacc = fmaf(breg[4 * kk + 1], hq.y, bacc);
                bacc = fmaf(breg[4 * kk + 2], hq.z, bacc);
                bacc = fmaf(breg[4 * kk + 3], hq.w, bacc);
            }
            Up[512 + lane] = bacc;
        }
    }
}

// ---------------------------------------------------------------------------
// Fused message aggregation + GRU. One wave per node; the two 32-lane halves
// process alternating in-edges (CSR by dst), accumulate m in registers,
// combine via shfl_xor(32). GRU: half 0 computes ih gates (x=m), half 1
// computes hh gates (x=h), combined via shfl_xor(32). No atomics, no memset,
// no m array. LDS: gate weights transposed, 24 KB.
// ---------------------------------------------------------------------------
__global__ __launch_bounds__(256)
void edge_gru_kernel(const int* __restrict__ ei,
                     const float* __restrict__ ef,
                     const float* __restrict__ U,
                     const int* __restrict__ rowptr,
                     const int* __restrict__ elist,
                     const float* __restrict__ Wih,
                     const float* __restrict__ Whh,
                     const float* __restrict__ bih,
                     const float* __restrict__ bhh,
                     const float* __restrict__ h,
                     float* __restrict__ hout) {
    __shared__ float WihT[H * 3 * H];   // [k*96 + gate*32 + i] : 12 KB
    __shared__ float WhhT[H * 3 * H];   // 12 KB
    for (int idx = threadIdx.x; idx < 3 * H * H; idx += 256) {
        int row = idx >> 5;
        int k   = idx & 31;
        WihT[k * 96 + row] = Wih[idx];
        WhhT[k * 96 + row] = Whh[idx];
    }
    __syncthreads();

    int lane = threadIdx.x & 63;
    int i    = lane & 31;
    int half = lane >> 5;
    int gw     = blockIdx.x * 4 + (threadIdx.x >> 6);
    int nwaves = gridDim.x * 4;

    for (int v = gw; v < N_NODES; v += nwaves) {
        int base = rowptr[v];
        int nE   = rowptr[v + 1] - base;

        float macc = 0.f;
        for (int j = half; j < nE; j += 2) {
            int e   = elist[base + j];
            int src = ei[e];
            const float* __restrict__ Up = U + (size_t)src * UROW;
            float efv = (i < EDGE_DIM) ? ef[e * EDGE_DIM + i] : 0.f;
            float s = Up[512 + i];                     // bias plane
#pragma unroll
            for (int d = 0; d < EDGE_DIM; ++d)
                s = fmaf(__shfl(efv, d, 32), Up[d * 32 + i], s);
            macc += s;
        }
        macc += __shfl_xor(macc, 32, 64);   // both halves now hold m[v,i]

        float hv = h[v * H + i];

        const float* __restrict__ Wb = half ? WhhT : WihT;
        const float* __restrict__ bb = half ? bhh  : bih;
        float xv = half ? hv : macc;
        float g0 = bb[i], g1 = bb[32 + i], g2 = bb[64 + i];
#pragma unroll
        for (int k = 0; k < H; ++k) {
            float xk = __shfl(xv, k, 32);
            g0 = fmaf(Wb[k * 96 + i],      xk, g0);
            g1 = fmaf(Wb[k * 96 + 32 + i], xk, g1);
            g2 = fmaf(Wb[k * 96 + 64 + i], xk, g2);
        }
        float r = 1.f / (1.f + __expf(-(g0 + __shfl_xor(g0, 32, 64))));
        float z = 1.f / (1.f + __expf(-(g1 + __shfl_xor(g1, 32, 64))));
        float o = __shfl_xor(g2, 32, 64);
        float in_ = half ? o  : g2;
        float hn  = half ? g2 : o;
        float nn = tanhf(in_ + r * hn);
        float hnew = (1.f - z) * nn + z * hv;
        if (half == 0) hout[v * H + i] = hnew;
    }
}

// ---------------------------------------------------------------------------
extern "C" void kernel_launch(void* const* d_in, const int* in_sizes, int n_in,
                              void* d_out, int out_size, void* d_ws, size_t ws_size,
                              hipStream_t stream) {
    const float* node_feat = (const float*)d_in[0];
    const int*   edge_idx  = (const int*)  d_in[1];
    const float* edge_feat = (const float*)d_in[2];
    const float* W_np      = (const float*)d_in[3];
    const float* b_np      = (const float*)d_in[4];
    const float* W_e       = (const float*)d_in[5];
    const float* b_e       = (const float*)d_in[6];
    const float* W_ih      = (const float*)d_in[7];
    const float* W_hh      = (const float*)d_in[8];
    const float* b_ih      = (const float*)d_in[9];
    const float* b_hh      = (const float*)d_in[10];

    float* h      = (float*)d_ws;                       // N*H
    float* U      = h + (size_t)N_NODES * H;            // N*544
    int*   rowptr = (int*)(U + (size_t)N_NODES * UROW); // N+1
    int*   cursor = rowptr + (N_NODES + 1);             // N (also deg)
    int*   bsum   = cursor + N_NODES;                   // 80
    int*   elist  = bsum + 80;                          // E
    float* out    = (float*)d_out;

    // ---- CSR by dst (edge_index is constant across steps) ----
    hipMemsetAsync(cursor, 0, N_NODES * sizeof(int), stream);
    hist_kernel<<<(N_EDGES + 255) / 256, 256, 0, stream>>>(edge_idx, cursor);
    scan_a_kernel<<<(N_NODES + 255) / 256, 256, 0, stream>>>(cursor, rowptr, bsum);
    scan_b_kernel<<<1, 256, 0, stream>>>(rowptr, bsum, cursor);
    fill_kernel<<<(N_EDGES + 255) / 256, 256, 0, stream>>>(edge_idx, cursor, elist);

    // ---- h0 ----
    node_proj_kernel<<<(N_NODES * H + 255) / 256, 256, 0, stream>>>(
        node_feat, W_np, b_np, h);

    // ---- 3 propagation steps ----
    for (int step = 0; step < STEPS; ++step) {
        u_precompute_kernel<<<625, 256, 0, stream>>>(W_e, b_e, h, U);
        float* dst_h = (step == STEPS - 1) ? out : h;
        edge_gru_kernel<<<2500, 256, 0, stream>>>(
            edge_idx, edge_feat, U, rowptr, elist,
            W_ih, W_hh, b_ih, b_hh, h, dst_h);
    }
}

// Round 4
// 382.258 us; speedup vs baseline: 2.5234x; 2.5234x over previous
//
#include <hip/hip_runtime.h>
#include <math.h>

#define N_NODES 20000
#define N_EDGES 160000
#define NODE_DIM 64
#define EDGE_DIM 16
#define H 32
#define STEPS 3
#define UROW 544   // U[v][c]: c = i*16+d for c<512 (i=c>>4,d=c&15); c=512+i is bias plane

// ---------------------------------------------------------------------------
// CSR-by-src build (once per call): hist -> 2-level scan -> atomic fill that
// directly emits sorted src2/dst2/eperm. Then ef is permuted into ef2.
// ---------------------------------------------------------------------------
__global__ void hist_kernel(const int* __restrict__ ei, int* __restrict__ deg) {
    int e = blockIdx.x * 256 + threadIdx.x;
    if (e < N_EDGES) atomicAdd(&deg[ei[e]], 1);   // row 0 = src
}

__global__ void scan_a_kernel(const int* __restrict__ deg,
                              int* __restrict__ part, int* __restrict__ bsum) {
    __shared__ int s[256];
    int v = blockIdx.x * 256 + threadIdx.x;
    int x = (v < N_NODES) ? deg[v] : 0;
    s[threadIdx.x] = x;
    __syncthreads();
    for (int off = 1; off < 256; off <<= 1) {
        int t = (threadIdx.x >= off) ? s[threadIdx.x - off] : 0;
        __syncthreads();
        s[threadIdx.x] += t;
        __syncthreads();
    }
    if (v < N_NODES) part[v] = s[threadIdx.x] - x;
    if (threadIdx.x == 255) bsum[blockIdx.x] = s[255];
}

__global__ void scan_b_kernel(int* __restrict__ rowptr,
                              const int* __restrict__ bsum,
                              int* __restrict__ cursor) {
    __shared__ int boff[80];
    if (threadIdx.x == 0) {
        int run = 0;
        for (int b = 0; b < 79; ++b) { boff[b] = run; run += bsum[b]; }
    }
    __syncthreads();
    for (int v = threadIdx.x; v < N_NODES; v += 256) {
        int r = rowptr[v] + boff[v >> 8];
        rowptr[v] = r;
        cursor[v] = r;
    }
    if (threadIdx.x == 0) rowptr[N_NODES] = N_EDGES;
}

__global__ void fill_kernel(const int* __restrict__ ei, int* __restrict__ cursor,
                            int* __restrict__ eperm, int* __restrict__ src2,
                            int* __restrict__ dst2) {
    int e = blockIdx.x * 256 + threadIdx.x;
    if (e < N_EDGES) {
        int s = ei[e];
        int slot = atomicAdd(&cursor[s], 1);
        eperm[slot] = e;
        src2[slot]  = s;
        dst2[slot]  = ei[N_EDGES + e];
    }
}

__global__ void permute_ef_kernel(const float* __restrict__ ef,
                                  const int* __restrict__ eperm,
                                  float* __restrict__ ef2) {
    int t = blockIdx.x * 256 + threadIdx.x;
    if (t < N_EDGES * EDGE_DIM) {
        int j = t >> 4;
        int d = t & 15;
        ef2[t] = ef[eperm[j] * EDGE_DIM + d];
    }
}

// ---------------------------------------------------------------------------
// node projection: h = node_feat @ W_np.T + b_np
// ---------------------------------------------------------------------------
__global__ void node_proj_kernel(const float* __restrict__ nf,
                                 const float* __restrict__ W,
                                 const float* __restrict__ b,
                                 float* __restrict__ h) {
    int tid = blockIdx.x * blockDim.x + threadIdx.x;
    if (tid >= N_NODES * H) return;
    int v = tid >> 5;
    int i = tid & 31;
    const float* __restrict__ row = nf + v * NODE_DIM;
    const float* __restrict__ w   = W + i * NODE_DIM;
    float acc = b[i];
#pragma unroll
    for (int d = 0; d < NODE_DIM; ++d) acc = fmaf(row[d], w[d], acc);
    h[tid] = acc;
}

// ---------------------------------------------------------------------------
// U precompute v3: U[v, c] = sum_k Wx[k][c] * h[v,k]
// where Wx[k][c] = We[((c>>4)*32+k)*16 + (c&15)]  (c < 512)
//                = be[(c-512)*32 + k]             (512 <= c < 544, bias plane)
// 576 threads/block, thread t owns column c=t (32 W regs; t>=544 idle on
// compute/store, helps stage). h rows staged in 4 KB LDS, read as pure
// same-address broadcast float4. 2 nodes/iter -> two independent FMA chains.
// Stores are b32 lane-consecutive (coalesced). VGPR ~48 -> high occupancy.
// ---------------------------------------------------------------------------
__global__ __launch_bounds__(576)
void u_precompute_kernel(const float* __restrict__ We,
                         const float* __restrict__ be,
                         const float* __restrict__ h,
                         float* __restrict__ U) {
    __shared__ float hs[32 * 32];   // 4 KB
    int t = threadIdx.x;
    int c = t;

    float wreg[32];
    if (c < 512) {
        int i = c >> 4, d = c & 15;
#pragma unroll
        for (int k = 0; k < H; ++k) wreg[k] = We[(i * H + k) * EDGE_DIM + d];
    } else if (c < UROW) {
        int i = c - 512;
#pragma unroll
        for (int k = 0; k < H; ++k) wreg[k] = be[i * H + k];
    }

    for (int v0 = blockIdx.x * 32; v0 < N_NODES; v0 += gridDim.x * 32) {
        __syncthreads();
        for (int idx = t; idx < 32 * 32; idx += 576) hs[idx] = h[v0 * H + idx];
        __syncthreads();

        for (int n = 0; n < 32; n += 2) {
            const float4* __restrict__ hp0 = (const float4*)(hs + n * H);
            const float4* __restrict__ hp1 = (const float4*)(hs + (n + 1) * H);
            float a0 = 0.f, a1 = 0.f;
#pragma unroll
            for (int kk = 0; kk < 8; ++kk) {
                float4 q0 = hp0[kk];
                float4 q1 = hp1[kk];
                a0 = fmaf(wreg[4 * kk + 0], q0.x, a0);
                a1 = fmaf(wreg[4 * kk + 0], q1.x, a1);
                a0 = fmaf(wreg[4 * kk + 1], q0.y, a0);
                a1 = fmaf(wreg[4 * kk + 1], q1.y, a1);
                a0 = fmaf(wreg[4 * kk + 2], q0.z, a0);
                a1 = fmaf(wreg[4 * kk + 2], q1.z, a1);
                a0 = fmaf(wreg[4 * kk + 3], q0.w, a0);
                a1 = fmaf(wreg[4 * kk + 3], q1.w, a1);
            }
            if (c < UROW) {
                U[(size_t)(v0 + n)     * UROW + c] = a0;
                U[(size_t)(v0 + n + 1) * UROW + c] = a1;
            }
        }
    }
}

// ---------------------------------------------------------------------------
// Edge message (src-sorted, edge-parallel, atomic scatter):
//   msg[j,i] = U[s,512+i] + sum_d ef2[j,d] * U[s, i*16+d]
// Consecutive half-waves share src rows (sorted) -> L1/L2 reuse of U.
// ---------------------------------------------------------------------------
__global__ __launch_bounds__(256)
void edge_msg_kernel(const int* __restrict__ src2,
                     const int* __restrict__ dst2,
                     const float* __restrict__ ef2,
                     const float* __restrict__ U,
                     float* __restrict__ m) {
    int tid  = blockIdx.x * blockDim.x + threadIdx.x;
    int j    = tid >> 5;
    int lane = tid & 31;
    if (j >= N_EDGES) return;

    int s  = src2[j];
    int dd = dst2[j];

    float efv = (lane < EDGE_DIM) ? ef2[j * EDGE_DIM + lane] : 0.f;

    const float* __restrict__ Up = U + (size_t)s * UROW;
    const float4* __restrict__ Urow = (const float4*)(Up + lane * EDGE_DIM);
    float4 u0 = Urow[0];
    float4 u1 = Urow[1];
    float4 u2 = Urow[2];
    float4 u3 = Urow[3];

    float msg = Up[512 + lane];   // bias plane
    msg = fmaf(__shfl(efv,  0, 32), u0.x, msg);
    msg = fmaf(__shfl(efv,  1, 32), u0.y, msg);
    msg = fmaf(__shfl(efv,  2, 32), u0.z, msg);
    msg = fmaf(__shfl(efv,  3, 32), u0.w, msg);
    msg = fmaf(__shfl(efv,  4, 32), u1.x, msg);
    msg = fmaf(__shfl(efv,  5, 32), u1.y, msg);
    msg = fmaf(__shfl(efv,  6, 32), u1.z, msg);
    msg = fmaf(__shfl(efv,  7, 32), u1.w, msg);
    msg = fmaf(__shfl(efv,  8, 32), u2.x, msg);
    msg = fmaf(__shfl(efv,  9, 32), u2.y, msg);
    msg = fmaf(__shfl(efv, 10, 32), u2.z, msg);
    msg = fmaf(__shfl(efv, 11, 32), u2.w, msg);
    msg = fmaf(__shfl(efv, 12, 32), u3.x, msg);
    msg = fmaf(__shfl(efv, 13, 32), u3.y, msg);
    msg = fmaf(__shfl(efv, 14, 32), u3.z, msg);
    msg = fmaf(__shfl(efv, 15, 32), u3.w, msg);

    atomicAdd(&m[dd * H + lane], msg);
}

// ---------------------------------------------------------------------------
// GRU cell (R2's verified version) + self-zero of m for the next step.
// ---------------------------------------------------------------------------
__global__ __launch_bounds__(256)
void gru_kernel(const float* __restrict__ Wih,
                const float* __restrict__ Whh,
                const float* __restrict__ bih,
                const float* __restrict__ bhh,
                float* __restrict__ m,
                const float* __restrict__ h,
                float* __restrict__ hout) {
    __shared__ float WihT[H * 3 * H];
    __shared__ float WhhT[H * 3 * H];
    for (int idx = threadIdx.x; idx < 3 * H * H; idx += 256) {
        int row = idx >> 5;
        int k   = idx & 31;
        WihT[k * (3 * H) + row] = Wih[idx];
        WhhT[k * (3 * H) + row] = Whh[idx];
    }
    __syncthreads();

    int lane = threadIdx.x & 31;
    int grp  = threadIdx.x >> 5;

    for (int v0 = blockIdx.x * 8; v0 < N_NODES; v0 += gridDim.x * 8) {
        int v = v0 + grp;
        if (v < N_NODES) {
            float mv = m[v * H + lane];
            m[v * H + lane] = 0.f;          // pre-zero for next step's atomics
            float hv = h[v * H + lane];
            float ir = bih[lane], iz = bih[H + lane], in_ = bih[2 * H + lane];
            float hr = bhh[lane], hz = bhh[H + lane], hn  = bhh[2 * H + lane];
#pragma unroll
            for (int k = 0; k < H; ++k) {
                float mk = __shfl(mv, k, 32);
                float hk = __shfl(hv, k, 32);
                ir  = fmaf(WihT[k * 96 + lane],          mk, ir);
                iz  = fmaf(WihT[k * 96 + H + lane],      mk, iz);
                in_ = fmaf(WihT[k * 96 + 2 * H + lane],  mk, in_);
                hr  = fmaf(WhhT[k * 96 + lane],          hk, hr);
                hz  = fmaf(WhhT[k * 96 + H + lane],      hk, hz);
                hn  = fmaf(WhhT[k * 96 + 2 * H + lane],  hk, hn);
            }
            float r  = 1.f / (1.f + __expf(-(ir + hr)));
            float z  = 1.f / (1.f + __expf(-(iz + hz)));
            float nn = tanhf(in_ + r * hn);
            hout[v * H + lane] = (1.f - z) * nn + z * hv;
        }
    }
}

// ---------------------------------------------------------------------------
extern "C" void kernel_launch(void* const* d_in, const int* in_sizes, int n_in,
                              void* d_out, int out_size, void* d_ws, size_t ws_size,
                              hipStream_t stream) {
    const float* node_feat = (const float*)d_in[0];
    const int*   edge_idx  = (const int*)  d_in[1];
    const float* edge_feat = (const float*)d_in[2];
    const float* W_np      = (const float*)d_in[3];
    const float* b_np      = (const float*)d_in[4];
    const float* W_e       = (const float*)d_in[5];
    const float* b_e       = (const float*)d_in[6];
    const float* W_ih      = (const float*)d_in[7];
    const float* W_hh      = (const float*)d_in[8];
    const float* b_ih      = (const float*)d_in[9];
    const float* b_hh      = (const float*)d_in[10];

    float* h      = (float*)d_ws;                         // 640000
    float* m      = h + (size_t)N_NODES * H;              // 640000
    float* U      = m + (size_t)N_NODES * H;              // 10,880,000
    float* ef2    = U + (size_t)N_NODES * UROW;           // 2,560,000
    int*   rowptr = (int*)(ef2 + (size_t)N_EDGES * EDGE_DIM); // N+1
    int*   cursor = rowptr + (N_NODES + 1);               // N
    int*   bsum   = cursor + N_NODES;                     // 80
    int*   eperm  = bsum + 80;                            // E
    int*   src2   = eperm + N_EDGES;                      // E
    int*   dst2   = src2 + N_EDGES;                       // E
    float* out    = (float*)d_out;

    // ---- one-time: zero m, build src-sorted edge arrays ----
    hipMemsetAsync(m, 0, (size_t)N_NODES * H * sizeof(float), stream);
    hipMemsetAsync(cursor, 0, N_NODES * sizeof(int), stream);
    hist_kernel<<<(N_EDGES + 255) / 256, 256, 0, stream>>>(edge_idx, cursor);
    scan_a_kernel<<<(N_NODES + 255) / 256, 256, 0, stream>>>(cursor, rowptr, bsum);
    scan_b_kernel<<<1, 256, 0, stream>>>(rowptr, bsum, cursor);
    fill_kernel<<<(N_EDGES + 255) / 256, 256, 0, stream>>>(edge_idx, cursor,
                                                           eperm, src2, dst2);
    permute_ef_kernel<<<(N_EDGES * EDGE_DIM + 255) / 256, 256, 0, stream>>>(
        edge_feat, eperm, ef2);

    // ---- h0 ----
    node_proj_kernel<<<(N_NODES * H + 255) / 256, 256, 0, stream>>>(
        node_feat, W_np, b_np, h);

    // ---- 3 propagation steps ----
    for (int step = 0; step < STEPS; ++step) {
        u_precompute_kernel<<<313, 576, 0, stream>>>(W_e, b_e, h, U);
        edge_msg_kernel<<<(N_EDGES * H + 255) / 256, 256, 0, stream>>>(
            src2, dst2, ef2, U, m);
        float* dst_h = (step == STEPS - 1) ? out : h;
        gru_kernel<<<256, 256, 0, stream>>>(W_ih, W_hh, b_ih, b_hh, m, h, dst_h);
    }
}